// Round 8
// baseline (366.853 us; speedup 1.0000x reference)
//
#include <hip/hip_runtime.h>
#include <hip/hip_bf16.h>

#define NN 16384
#define TT 4
#define HH 64
#define NT (NN * TT)
#define NEG_SLOPE 0.2f
#define LN_EPS 1e-5f

typedef __attribute__((ext_vector_type(8))) short short8;   // 8 bf16 (4 VGPRs)
typedef __attribute__((ext_vector_type(4))) float f32x4;    // MFMA accumulator

__device__ __forceinline__ float bf2f(unsigned short u) {
    return __uint_as_float((unsigned)u << 16);
}
// f32 -> bf16 RNE
__device__ __forceinline__ unsigned short f2bf(float f) {
    unsigned u = __float_as_uint(f);
    return (unsigned short)((u + 0x7FFF + ((u >> 16) & 1)) >> 16);
}

// ---------------- CSR build (both edge sets fused) ----------------

__global__ void zero_kernel(int* __restrict__ a, int n) {
    int i = blockIdx.x * blockDim.x + threadIdx.x;
    if (i < n) a[i] = 0;
}

__global__ void hist2_kernel(const int* __restrict__ dst_s, const int* __restrict__ dst_f,
                             int* __restrict__ cnt2, int E) {
    int e = blockIdx.x * blockDim.x + threadIdx.x;
    if (e < E) {
        atomicAdd(&cnt2[dst_s[e]], 1);
    } else {
        e -= E;
        if (e < E) atomicAdd(&cnt2[NN + dst_f[e]], 1);
    }
}

// --- fully parallel 3-phase exclusive scan of cnt2 (2 sets x NN) ---
__global__ __launch_bounds__(256) void scanA_kernel(const int* __restrict__ cnt2,
                                                    int* __restrict__ partial) {
    __shared__ int wsum[4];
    const int lane = threadIdx.x & 63;
    const int wv = threadIdx.x >> 6;
    int v = cnt2[blockIdx.x * 256 + threadIdx.x];
#pragma unroll
    for (int off = 32; off > 0; off >>= 1) v += __shfl_xor(v, off, 64);
    if (lane == 0) wsum[wv] = v;
    __syncthreads();
    if (threadIdx.x == 0)
        partial[blockIdx.x] = wsum[0] + wsum[1] + wsum[2] + wsum[3];
}

__global__ __launch_bounds__(128) void scanB_kernel(int* __restrict__ partial) {
    const int lane = threadIdx.x & 63;
    int v = partial[threadIdx.x];
    int inc = v;
#pragma unroll
    for (int off = 1; off < 64; off <<= 1) {
        int t = __shfl_up(inc, off, 64);
        if (lane >= off) inc += t;
    }
    partial[threadIdx.x] = inc - v;
}

__global__ __launch_bounds__(256) void scanC_kernel(const int* __restrict__ cnt2,
                                                    const int* __restrict__ partial,
                                                    int* __restrict__ rp2,
                                                    int* __restrict__ cur2) {
    __shared__ int wsum[4];
    const int lane = threadIdx.x & 63;
    const int wv = threadIdx.x >> 6;
    const int gidx = blockIdx.x * 256 + threadIdx.x;
    const int set = gidx >> 14;
    const int i = gidx & (NN - 1);
    int v = cnt2[gidx];
    int inc = v;
#pragma unroll
    for (int off = 1; off < 64; off <<= 1) {
        int t = __shfl_up(inc, off, 64);
        if (lane >= off) inc += t;
    }
    if (lane == 63) wsum[wv] = inc;
    __syncthreads();
    int wbase = 0;
#pragma unroll
    for (int w = 0; w < 4; w++)
        if (w < wv) wbase += wsum[w];
    int excl = (inc - v) + wbase + partial[blockIdx.x];
    int* rp = rp2 + set * (NN + 1);
    rp[i] = excl;
    cur2[gidx] = excl;
    if (i == NN - 1) rp[NN] = excl + v;
}

__global__ void scatter2_kernel(const int* __restrict__ ei_s, const int* __restrict__ ei_f,
                                int* __restrict__ cur2, int* __restrict__ col2, int E) {
    int e = blockIdx.x * blockDim.x + threadIdx.x;
    if (e < E) {
        int d = ei_s[E + e];
        int pos = atomicAdd(&cur2[d], 1);
        col2[pos] = ei_s[e];
    } else {
        e -= E;
        if (e < E) {
            int d = ei_f[E + e];
            int pos = atomicAdd(&cur2[NN + d], 1);
            col2[E + pos] = ei_f[e];
        }
    }
}

// ------- fused dual transform via MFMA: h_s = x*Ws, h_f = x*Wf + scores ------
// h and sc stored T-MAJOR: h[t][node][ch], sc[t][node] (per-t 2 MB slices so
// one XCD L2 can hold a t-slice during aggregation).

__global__ __launch_bounds__(256) void transform2_kernel(
    const float4* __restrict__ x4,
    const float* __restrict__ Ws, const float* __restrict__ as_,
    const float* __restrict__ Wf, const float* __restrict__ af,
    unsigned short* __restrict__ h_s, float* __restrict__ sc_s,
    unsigned short* __restrict__ h_f, float* __restrict__ sc_f) {
    const int lane = threadIdx.x & 63;
    const int wv = threadIdx.x >> 6;
    const int m = lane & 15;
    const int quad = lane >> 4;

    short8 Bs[4][2], Bf[4][2];
#pragma unroll
    for (int c = 0; c < 4; c++) {
#pragma unroll
        for (int ks = 0; ks < 2; ks++) {
#pragma unroll
            for (int j = 0; j < 8; j++) {
                int k = ks * 32 + quad * 8 + j;
                int n = c * 16 + m;
                Bs[c][ks][j] = (short)f2bf(Ws[k * 64 + n]);
                Bf[c][ks][j] = (short)f2bf(Wf[k * 64 + n]);
            }
        }
    }
    float a_s[4], a_f[4];
#pragma unroll
    for (int c = 0; c < 4; c++) { a_s[c] = as_[c * 16 + m]; a_f[c] = af[c * 16 + m]; }

    const int rowbase = blockIdx.x * 128 + wv * 32;
#pragma unroll
    for (int rt = 0; rt < 2; rt++) {
        const int row0 = rowbase + rt * 16;
        const long xbase = (long)(row0 + m) * 16 + quad * 2;
        float4 xa = x4[xbase];
        float4 xb = x4[xbase + 1];
        float4 xc = x4[xbase + 8];
        float4 xd = x4[xbase + 9];
        short8 A0, A1;
        A0[0] = (short)f2bf(xa.x); A0[1] = (short)f2bf(xa.y);
        A0[2] = (short)f2bf(xa.z); A0[3] = (short)f2bf(xa.w);
        A0[4] = (short)f2bf(xb.x); A0[5] = (short)f2bf(xb.y);
        A0[6] = (short)f2bf(xb.z); A0[7] = (short)f2bf(xb.w);
        A1[0] = (short)f2bf(xc.x); A1[1] = (short)f2bf(xc.y);
        A1[2] = (short)f2bf(xc.z); A1[3] = (short)f2bf(xc.w);
        A1[4] = (short)f2bf(xd.x); A1[5] = (short)f2bf(xd.y);
        A1[6] = (short)f2bf(xd.z); A1[7] = (short)f2bf(xd.w);

        f32x4 accs[4], accf[4];
#pragma unroll
        for (int c = 0; c < 4; c++) {
            accs[c] = (f32x4){0.f, 0.f, 0.f, 0.f};
            accf[c] = (f32x4){0.f, 0.f, 0.f, 0.f};
        }
#pragma unroll
        for (int c = 0; c < 4; c++) {
            accs[c] = __builtin_amdgcn_mfma_f32_16x16x32_bf16(A0, Bs[c][0], accs[c], 0, 0, 0);
            accs[c] = __builtin_amdgcn_mfma_f32_16x16x32_bf16(A1, Bs[c][1], accs[c], 0, 0, 0);
            accf[c] = __builtin_amdgcn_mfma_f32_16x16x32_bf16(A0, Bf[c][0], accf[c], 0, 0, 0);
            accf[c] = __builtin_amdgcn_mfma_f32_16x16x32_bf16(A1, Bf[c][1], accf[c], 0, 0, 0);
        }
#pragma unroll
        for (int reg = 0; reg < 4; reg++) {
            const int row = row0 + quad * 4 + reg;
            const int node = row >> 2;
            const int tt = row & 3;
            const long hb = ((long)tt * NN + node) * 64;
            float ps = 0.f, pf = 0.f;
#pragma unroll
            for (int c = 0; c < 4; c++) {
                h_s[hb + c * 16 + m] = f2bf(accs[c][reg]);
                h_f[hb + c * 16 + m] = f2bf(accf[c][reg]);
                ps = fmaf(accs[c][reg], a_s[c], ps);
                pf = fmaf(accf[c][reg], a_f[c], pf);
            }
#pragma unroll
            for (int off = 1; off < 16; off <<= 1) {
                ps += __shfl_xor(ps, off, 64);
                pf += __shfl_xor(pf, off, 64);
            }
            if (m == 0) {
                sc_s[tt * NN + node] = (ps > 0.f) ? ps : NEG_SLOPE * ps;
                sc_f[tt * NN + node] = (pf > 0.f) ? pf : NEG_SLOPE * pf;
            }
        }
    }
}

// ---------------- attention aggregation (per-t sliced) ----------------
// Grid = 2*NN blocks. blockIdx%8 -> (t, node-half): XCD round-robin keeps each
// XCD on one t's 4 MB h-slice. Block = 4 waves = 2 nodes x 2 sets (one t).
// Lane = (u = lane>>4 edge-in-quad, ci = lane&15 channel-quad): 4 edges per
// ushort4 load instruction, exactly 1 cache line per edge.

__global__ __launch_bounds__(256) void aggregate_kernel(
    const float4* __restrict__ x4,
    const ushort4* __restrict__ hs4, const float* __restrict__ scs,
    const int* __restrict__ rps, const int* __restrict__ cols,
    const ushort4* __restrict__ hf4, const float* __restrict__ scf,
    const int* __restrict__ rpf, const int* __restrict__ colf,
    const float4* __restrict__ g4, const float4* __restrict__ b4,
    float4* __restrict__ out4) {
    __shared__ float4 msgF[2][16];
    const int wv = threadIdx.x >> 6;
    const int lane = threadIdx.x & 63;
    const int slot = wv >> 1;              // node slot in block (0/1)
    const int set = wv & 1;                // 0 = structural, 1 = functional
    const int r = blockIdx.x & 7;
    const int t = r >> 1;
    const int half = r & 1;
    const int n = half * (NN / 2) + (blockIdx.x >> 3) * 2 + slot;
    const int u = lane >> 4;
    const int ci = lane & 15;

    const ushort4* h4 = set ? hf4 : hs4;
    const float* sc = set ? scf : scs;
    const int* rp = set ? rpf : rps;
    const int* col = set ? colf : cols;

    const float* sct = sc + t * NN;
    const ushort4* ht = h4 + (size_t)t * NN * 16;

    const int beg = rp[n], end = rp[n + 1];
    float den = 0.f;
    float4 acc = {0.f, 0.f, 0.f, 0.f};
    for (int j = beg; j < end; j += 4) {
        const int je = j + u;
        const bool ok = (je < end);
        int s0 = ok ? col[je] : col[beg];
        float l = ok ? sct[s0] : -INFINITY;    // exp -> 0 for pad lanes
        ushort4 hh = ht[s0 * 16 + ci];
        float e = __expf(l);
        den += e;
        acc.x = fmaf(e, bf2f(hh.x), acc.x);
        acc.y = fmaf(e, bf2f(hh.y), acc.y);
        acc.z = fmaf(e, bf2f(hh.z), acc.z);
        acc.w = fmaf(e, bf2f(hh.w), acc.w);
    }
    // combine the 4 u-groups (xor 16, 32 stay within same ci)
#pragma unroll
    for (int off = 16; off < 64; off <<= 1) {
        den += __shfl_xor(den, off, 64);
        acc.x += __shfl_xor(acc.x, off, 64);
        acc.y += __shfl_xor(acc.y, off, 64);
        acc.z += __shfl_xor(acc.z, off, 64);
        acc.w += __shfl_xor(acc.w, off, 64);
    }
    float4 msg;
    if (end > beg) {
        float rd = 1.f / den;
        msg.x = acc.x * rd; msg.y = acc.y * rd; msg.z = acc.z * rd; msg.w = acc.w * rd;
    } else {
        msg.x = msg.y = msg.z = msg.w = 0.f;
    }

    if (set == 1 && u == 0) msgF[slot][ci] = msg;
    __syncthreads();
    if (set == 1) return;

    float4 mf = msgF[slot][ci];
    float4 xv = x4[(n * 4 + t) * 16 + ci];   // x[n][t][4*ci..+3]

    float v0 = xv.x + 0.5f * (msg.x + mf.x);
    float v1 = xv.y + 0.5f * (msg.y + mf.y);
    float v2 = xv.z + 0.5f * (msg.z + mf.z);
    float v3 = xv.w + 0.5f * (msg.w + mf.w);

    // LayerNorm over H=64 within the 16-lane ci group (all u groups identical)
    float sum = (v0 + v1) + (v2 + v3);
#pragma unroll
    for (int off = 1; off < 16; off <<= 1) sum += __shfl_xor(sum, off, 64);
    float mu = sum * (1.f / 64.f);
    float d0 = v0 - mu, d1 = v1 - mu, d2 = v2 - mu, d3 = v3 - mu;
    float var = (d0 * d0 + d1 * d1) + (d2 * d2 + d3 * d3);
#pragma unroll
    for (int off = 1; off < 16; off <<= 1) var += __shfl_xor(var, off, 64);
    var *= (1.f / 64.f);
    float inv = rsqrtf(var + LN_EPS);
    float4 gv = g4[ci], bv = b4[ci];
    float4 o;
    o.x = d0 * inv * gv.x + bv.x;
    o.y = d1 * inv * gv.y + bv.y;
    o.z = d2 * inv * gv.z + bv.z;
    o.w = d3 * inv * gv.w + bv.w;
    if (u == 0) out4[(n * 4 + t) * 16 + ci] = o;
}

// ---------------- launch ----------------

extern "C" void kernel_launch(void* const* d_in, const int* in_sizes, int n_in,
                              void* d_out, int out_size, void* d_ws, size_t ws_size,
                              hipStream_t stream) {
    const float* pred = (const float*)d_in[0];
    const int* ei_s = (const int*)d_in[1];
    const int* ei_f = (const int*)d_in[2];
    const float* W0s = (const float*)d_in[3];
    const float* a0s = (const float*)d_in[4];
    const float* W0f = (const float*)d_in[5];
    const float* a0f = (const float*)d_in[6];
    const float* g0  = (const float*)d_in[7];
    const float* b0  = (const float*)d_in[8];
    const float* W1s = (const float*)d_in[9];
    const float* a1s = (const float*)d_in[10];
    const float* W1f = (const float*)d_in[11];
    const float* a1f = (const float*)d_in[12];
    const float* g1  = (const float*)d_in[13];
    const float* b1  = (const float*)d_in[14];
    const int E = in_sizes[1] / 2;  // 262144

    char* ws = (char*)d_ws;
    auto alloc = [&](size_t bytes) {
        char* p = ws;
        ws += (bytes + 255) & ~(size_t)255;
        return p;
    };
    int* cnt2 = (int*)alloc((size_t)2 * NN * sizeof(int));
    int* rp2  = (int*)alloc((size_t)2 * (NN + 1) * sizeof(int));
    int* cur2 = (int*)alloc((size_t)2 * NN * sizeof(int));
    int* col2 = (int*)alloc((size_t)2 * E * sizeof(int));
    int* partial = (int*)alloc(128 * sizeof(int));
    unsigned short* h_s = (unsigned short*)alloc((size_t)NT * HH * sizeof(unsigned short));
    unsigned short* h_f = (unsigned short*)alloc((size_t)NT * HH * sizeof(unsigned short));
    float* sc_s = (float*)alloc((size_t)NT * sizeof(float));
    float* sc_f = (float*)alloc((size_t)NT * sizeof(float));
    float* x_mid = (float*)alloc((size_t)NT * HH * sizeof(float));

    const int* rp_s = rp2;
    const int* rp_f = rp2 + (NN + 1);
    const int* col_s = col2;
    const int* col_f = col2 + E;

    const int EB = (E + 255) / 256;

    zero_kernel<<<(2 * NN) / 256, 256, 0, stream>>>(cnt2, 2 * NN);
    hist2_kernel<<<2 * EB, 256, 0, stream>>>(ei_s + E, ei_f + E, cnt2, E);
    scanA_kernel<<<128, 256, 0, stream>>>(cnt2, partial);
    scanB_kernel<<<1, 128, 0, stream>>>(partial);
    scanC_kernel<<<128, 256, 0, stream>>>(cnt2, partial, rp2, cur2);
    scatter2_kernel<<<2 * EB, 256, 0, stream>>>(ei_s, ei_f, cur2, col2, E);

    // layer 0
    transform2_kernel<<<NT / 128, 256, 0, stream>>>(
        (const float4*)pred, W0s, a0s, W0f, a0f, h_s, sc_s, h_f, sc_f);
    aggregate_kernel<<<2 * NN, 256, 0, stream>>>(
        (const float4*)pred, (const ushort4*)h_s, sc_s, rp_s, col_s,
        (const ushort4*)h_f, sc_f, rp_f, col_f,
        (const float4*)g0, (const float4*)b0, (float4*)x_mid);

    // layer 1
    transform2_kernel<<<NT / 128, 256, 0, stream>>>(
        (const float4*)x_mid, W1s, a1s, W1f, a1f, h_s, sc_s, h_f, sc_f);
    aggregate_kernel<<<2 * NN, 256, 0, stream>>>(
        (const float4*)x_mid, (const ushort4*)h_s, sc_s, rp_s, col_s,
        (const ushort4*)h_f, sc_f, rp_f, col_f,
        (const float4*)g1, (const float4*)b1, (float4*)d_out);
}

// Round 9
// 286.859 us; speedup vs baseline: 1.2789x; 1.2789x over previous
//
#include <hip/hip_runtime.h>
#include <hip/hip_bf16.h>

#define NN 16384
#define TT 4
#define HH 64
#define NT (NN * TT)
#define NEG_SLOPE 0.2f
#define LN_EPS 1e-5f

typedef __attribute__((ext_vector_type(8))) short short8;   // 8 bf16 (4 VGPRs)
typedef __attribute__((ext_vector_type(4))) float f32x4;    // MFMA accumulator

__device__ __forceinline__ float bf2f(unsigned short u) {
    return __uint_as_float((unsigned)u << 16);
}
// f32 -> bf16 RNE
__device__ __forceinline__ unsigned short f2bf(float f) {
    unsigned u = __float_as_uint(f);
    return (unsigned short)((u + 0x7FFF + ((u >> 16) & 1)) >> 16);
}

// ---------------- CSR build (both edge sets fused) ----------------

__global__ void zero_kernel(int* __restrict__ a, int n) {
    int i = blockIdx.x * blockDim.x + threadIdx.x;
    if (i < n) a[i] = 0;
}

__global__ void hist2_kernel(const int* __restrict__ dst_s, const int* __restrict__ dst_f,
                             int* __restrict__ cnt2, int E) {
    int e = blockIdx.x * blockDim.x + threadIdx.x;
    if (e < E) {
        atomicAdd(&cnt2[dst_s[e]], 1);
    } else {
        e -= E;
        if (e < E) atomicAdd(&cnt2[NN + dst_f[e]], 1);
    }
}

// --- fully parallel 3-phase exclusive scan of cnt2 (2 sets x NN) ---
__global__ __launch_bounds__(256) void scanA_kernel(const int* __restrict__ cnt2,
                                                    int* __restrict__ partial) {
    __shared__ int wsum[4];
    const int lane = threadIdx.x & 63;
    const int wv = threadIdx.x >> 6;
    int v = cnt2[blockIdx.x * 256 + threadIdx.x];
#pragma unroll
    for (int off = 32; off > 0; off >>= 1) v += __shfl_xor(v, off, 64);
    if (lane == 0) wsum[wv] = v;
    __syncthreads();
    if (threadIdx.x == 0)
        partial[blockIdx.x] = wsum[0] + wsum[1] + wsum[2] + wsum[3];
}

__global__ __launch_bounds__(128) void scanB_kernel(int* __restrict__ partial) {
    const int lane = threadIdx.x & 63;
    int v = partial[threadIdx.x];
    int inc = v;
#pragma unroll
    for (int off = 1; off < 64; off <<= 1) {
        int t = __shfl_up(inc, off, 64);
        if (lane >= off) inc += t;
    }
    partial[threadIdx.x] = inc - v;
}

__global__ __launch_bounds__(256) void scanC_kernel(const int* __restrict__ cnt2,
                                                    const int* __restrict__ partial,
                                                    int* __restrict__ rp2,
                                                    int* __restrict__ cur2) {
    __shared__ int wsum[4];
    const int lane = threadIdx.x & 63;
    const int wv = threadIdx.x >> 6;
    const int gidx = blockIdx.x * 256 + threadIdx.x;
    const int set = gidx >> 14;
    const int i = gidx & (NN - 1);
    int v = cnt2[gidx];
    int inc = v;
#pragma unroll
    for (int off = 1; off < 64; off <<= 1) {
        int t = __shfl_up(inc, off, 64);
        if (lane >= off) inc += t;
    }
    if (lane == 63) wsum[wv] = inc;
    __syncthreads();
    int wbase = 0;
#pragma unroll
    for (int w = 0; w < 4; w++)
        if (w < wv) wbase += wsum[w];
    int excl = (inc - v) + wbase + partial[blockIdx.x];
    int* rp = rp2 + set * (NN + 1);
    rp[i] = excl;
    cur2[gidx] = excl;
    if (i == NN - 1) rp[NN] = excl + v;
}

__global__ void scatter2_kernel(const int* __restrict__ ei_s, const int* __restrict__ ei_f,
                                int* __restrict__ cur2, int* __restrict__ col2, int E) {
    int e = blockIdx.x * blockDim.x + threadIdx.x;
    if (e < E) {
        int d = ei_s[E + e];
        int pos = atomicAdd(&cur2[d], 1);
        col2[pos] = ei_s[e];
    } else {
        e -= E;
        if (e < E) {
            int d = ei_f[E + e];
            int pos = atomicAdd(&cur2[NN + d], 1);
            col2[E + pos] = ei_f[e];
        }
    }
}

// ------- fused dual transform via MFMA: h_s = x*Ws, h_f = x*Wf + scores ------
// h and sc stored T-MAJOR: h[t][node][ch], sc[t][node] (per-t 2 MB slices so
// one XCD L2 can hold a t-slice during aggregation).

__global__ __launch_bounds__(256) void transform2_kernel(
    const float4* __restrict__ x4,
    const float* __restrict__ Ws, const float* __restrict__ as_,
    const float* __restrict__ Wf, const float* __restrict__ af,
    unsigned short* __restrict__ h_s, float* __restrict__ sc_s,
    unsigned short* __restrict__ h_f, float* __restrict__ sc_f) {
    const int lane = threadIdx.x & 63;
    const int wv = threadIdx.x >> 6;
    const int m = lane & 15;
    const int quad = lane >> 4;

    short8 Bs[4][2], Bf[4][2];
#pragma unroll
    for (int c = 0; c < 4; c++) {
#pragma unroll
        for (int ks = 0; ks < 2; ks++) {
#pragma unroll
            for (int j = 0; j < 8; j++) {
                int k = ks * 32 + quad * 8 + j;
                int n = c * 16 + m;
                Bs[c][ks][j] = (short)f2bf(Ws[k * 64 + n]);
                Bf[c][ks][j] = (short)f2bf(Wf[k * 64 + n]);
            }
        }
    }
    float a_s[4], a_f[4];
#pragma unroll
    for (int c = 0; c < 4; c++) { a_s[c] = as_[c * 16 + m]; a_f[c] = af[c * 16 + m]; }

    const int rowbase = blockIdx.x * 128 + wv * 32;
#pragma unroll
    for (int rt = 0; rt < 2; rt++) {
        const int row0 = rowbase + rt * 16;
        const long xbase = (long)(row0 + m) * 16 + quad * 2;
        float4 xa = x4[xbase];
        float4 xb = x4[xbase + 1];
        float4 xc = x4[xbase + 8];
        float4 xd = x4[xbase + 9];
        short8 A0, A1;
        A0[0] = (short)f2bf(xa.x); A0[1] = (short)f2bf(xa.y);
        A0[2] = (short)f2bf(xa.z); A0[3] = (short)f2bf(xa.w);
        A0[4] = (short)f2bf(xb.x); A0[5] = (short)f2bf(xb.y);
        A0[6] = (short)f2bf(xb.z); A0[7] = (short)f2bf(xb.w);
        A1[0] = (short)f2bf(xc.x); A1[1] = (short)f2bf(xc.y);
        A1[2] = (short)f2bf(xc.z); A1[3] = (short)f2bf(xc.w);
        A1[4] = (short)f2bf(xd.x); A1[5] = (short)f2bf(xd.y);
        A1[6] = (short)f2bf(xd.z); A1[7] = (short)f2bf(xd.w);

        f32x4 accs[4], accf[4];
#pragma unroll
        for (int c = 0; c < 4; c++) {
            accs[c] = (f32x4){0.f, 0.f, 0.f, 0.f};
            accf[c] = (f32x4){0.f, 0.f, 0.f, 0.f};
        }
#pragma unroll
        for (int c = 0; c < 4; c++) {
            accs[c] = __builtin_amdgcn_mfma_f32_16x16x32_bf16(A0, Bs[c][0], accs[c], 0, 0, 0);
            accs[c] = __builtin_amdgcn_mfma_f32_16x16x32_bf16(A1, Bs[c][1], accs[c], 0, 0, 0);
            accf[c] = __builtin_amdgcn_mfma_f32_16x16x32_bf16(A0, Bf[c][0], accf[c], 0, 0, 0);
            accf[c] = __builtin_amdgcn_mfma_f32_16x16x32_bf16(A1, Bf[c][1], accf[c], 0, 0, 0);
        }
#pragma unroll
        for (int reg = 0; reg < 4; reg++) {
            const int row = row0 + quad * 4 + reg;
            const int node = row >> 2;
            const int tt = row & 3;
            const long hb = ((long)tt * NN + node) * 64;
            float ps = 0.f, pf = 0.f;
#pragma unroll
            for (int c = 0; c < 4; c++) {
                h_s[hb + c * 16 + m] = f2bf(accs[c][reg]);
                h_f[hb + c * 16 + m] = f2bf(accf[c][reg]);
                ps = fmaf(accs[c][reg], a_s[c], ps);
                pf = fmaf(accf[c][reg], a_f[c], pf);
            }
#pragma unroll
            for (int off = 1; off < 16; off <<= 1) {
                ps += __shfl_xor(ps, off, 64);
                pf += __shfl_xor(pf, off, 64);
            }
            if (m == 0) {
                sc_s[tt * NN + node] = (ps > 0.f) ? ps : NEG_SLOPE * ps;
                sc_f[tt * NN + node] = (pf > 0.f) ? pf : NEG_SLOPE * pf;
            }
        }
    }
}

// ---------------- attention aggregation (per-t sliced, unrolled) ----------------
// Grid = 2*NN blocks. blockIdx%8 -> (t, node-half): XCD round-robin keeps each
// XCD on one t's 4 MB h-slice. Block = 4 waves = 2 nodes x 2 sets (one t).
// Lane = (u = lane>>4, ci = lane&15). Inner loop: 16 edges per iteration
// (4 per u-group, unroll 4) with ALL loads issued before any use; invalid
// edges use clamped index + exp(-inf)=0 weight, so typical deg<=16 is a
// single full-MLP iteration (12 loads in flight/lane).

__global__ __launch_bounds__(256) void aggregate_kernel(
    const float4* __restrict__ x4,
    const ushort4* __restrict__ hs4, const float* __restrict__ scs,
    const int* __restrict__ rps, const int* __restrict__ cols,
    const ushort4* __restrict__ hf4, const float* __restrict__ scf,
    const int* __restrict__ rpf, const int* __restrict__ colf,
    const float4* __restrict__ g4, const float4* __restrict__ b4,
    float4* __restrict__ out4) {
    __shared__ float4 msgF[2][16];
    const int wv = threadIdx.x >> 6;
    const int lane = threadIdx.x & 63;
    const int slot = wv >> 1;              // node slot in block (0/1)
    const int set = wv & 1;                // 0 = structural, 1 = functional
    const int r = blockIdx.x & 7;
    const int t = r >> 1;
    const int half = r & 1;
    const int n = half * (NN / 2) + (blockIdx.x >> 3) * 2 + slot;
    const int u = lane >> 4;
    const int ci = lane & 15;

    const ushort4* h4 = set ? hf4 : hs4;
    const float* sc = set ? scf : scs;
    const int* rp = set ? rpf : rps;
    const int* col = set ? colf : cols;

    const float* sct = sc + t * NN;
    const ushort4* ht = h4 + (size_t)t * NN * 16;

    const int beg = rp[n], end = rp[n + 1];
    float den = 0.f;
    float4 acc = {0.f, 0.f, 0.f, 0.f};
    for (int j = beg; j < end; j += 16) {
        // edge je_k = j + k*4 + u; clamp invalid to beg, weight -> 0
        int je[4], s[4];
        bool ok[4];
        float l[4];
        ushort4 hh[4];
#pragma unroll
        for (int k = 0; k < 4; k++) {
            je[k] = j + k * 4 + u;
            ok[k] = je[k] < end;
            s[k] = col[ok[k] ? je[k] : beg];
        }
#pragma unroll
        for (int k = 0; k < 4; k++) l[k] = sct[s[k]];
#pragma unroll
        for (int k = 0; k < 4; k++) hh[k] = ht[s[k] * 16 + ci];
#pragma unroll
        for (int k = 0; k < 4; k++) {
            float e = ok[k] ? __expf(l[k]) : 0.f;
            den += e;
            acc.x = fmaf(e, bf2f(hh[k].x), acc.x);
            acc.y = fmaf(e, bf2f(hh[k].y), acc.y);
            acc.z = fmaf(e, bf2f(hh[k].z), acc.z);
            acc.w = fmaf(e, bf2f(hh[k].w), acc.w);
        }
    }
    // combine the 4 u-groups (xor 16, 32 stay within same ci)
#pragma unroll
    for (int off = 16; off < 64; off <<= 1) {
        den += __shfl_xor(den, off, 64);
        acc.x += __shfl_xor(acc.x, off, 64);
        acc.y += __shfl_xor(acc.y, off, 64);
        acc.z += __shfl_xor(acc.z, off, 64);
        acc.w += __shfl_xor(acc.w, off, 64);
    }
    float4 msg;
    if (end > beg) {
        float rd = 1.f / den;
        msg.x = acc.x * rd; msg.y = acc.y * rd; msg.z = acc.z * rd; msg.w = acc.w * rd;
    } else {
        msg.x = msg.y = msg.z = msg.w = 0.f;
    }

    if (set == 1 && u == 0) msgF[slot][ci] = msg;
    __syncthreads();
    if (set == 1) return;

    float4 mf = msgF[slot][ci];
    float4 xv = x4[(n * 4 + t) * 16 + ci];   // x[n][t][4*ci..+3]

    float v0 = xv.x + 0.5f * (msg.x + mf.x);
    float v1 = xv.y + 0.5f * (msg.y + mf.y);
    float v2 = xv.z + 0.5f * (msg.z + mf.z);
    float v3 = xv.w + 0.5f * (msg.w + mf.w);

    // LayerNorm over H=64 within the 16-lane ci group (all u groups identical)
    float sum = (v0 + v1) + (v2 + v3);
#pragma unroll
    for (int off = 1; off < 16; off <<= 1) sum += __shfl_xor(sum, off, 64);
    float mu = sum * (1.f / 64.f);
    float d0 = v0 - mu, d1 = v1 - mu, d2 = v2 - mu, d3 = v3 - mu;
    float var = (d0 * d0 + d1 * d1) + (d2 * d2 + d3 * d3);
#pragma unroll
    for (int off = 1; off < 16; off <<= 1) var += __shfl_xor(var, off, 64);
    var *= (1.f / 64.f);
    float inv = rsqrtf(var + LN_EPS);
    float4 gv = g4[ci], bv = b4[ci];
    float4 o;
    o.x = d0 * inv * gv.x + bv.x;
    o.y = d1 * inv * gv.y + bv.y;
    o.z = d2 * inv * gv.z + bv.z;
    o.w = d3 * inv * gv.w + bv.w;
    if (u == 0) out4[(n * 4 + t) * 16 + ci] = o;
}

// ---------------- launch ----------------

extern "C" void kernel_launch(void* const* d_in, const int* in_sizes, int n_in,
                              void* d_out, int out_size, void* d_ws, size_t ws_size,
                              hipStream_t stream) {
    const float* pred = (const float*)d_in[0];
    const int* ei_s = (const int*)d_in[1];
    const int* ei_f = (const int*)d_in[2];
    const float* W0s = (const float*)d_in[3];
    const float* a0s = (const float*)d_in[4];
    const float* W0f = (const float*)d_in[5];
    const float* a0f = (const float*)d_in[6];
    const float* g0  = (const float*)d_in[7];
    const float* b0  = (const float*)d_in[8];
    const float* W1s = (const float*)d_in[9];
    const float* a1s = (const float*)d_in[10];
    const float* W1f = (const float*)d_in[11];
    const float* a1f = (const float*)d_in[12];
    const float* g1  = (const float*)d_in[13];
    const float* b1  = (const float*)d_in[14];
    const int E = in_sizes[1] / 2;  // 262144

    char* ws = (char*)d_ws;
    auto alloc = [&](size_t bytes) {
        char* p = ws;
        ws += (bytes + 255) & ~(size_t)255;
        return p;
    };
    int* cnt2 = (int*)alloc((size_t)2 * NN * sizeof(int));
    int* rp2  = (int*)alloc((size_t)2 * (NN + 1) * sizeof(int));
    int* cur2 = (int*)alloc((size_t)2 * NN * sizeof(int));
    int* col2 = (int*)alloc((size_t)2 * E * sizeof(int));
    int* partial = (int*)alloc(128 * sizeof(int));
    unsigned short* h_s = (unsigned short*)alloc((size_t)NT * HH * sizeof(unsigned short));
    unsigned short* h_f = (unsigned short*)alloc((size_t)NT * HH * sizeof(unsigned short));
    float* sc_s = (float*)alloc((size_t)NT * sizeof(float));
    float* sc_f = (float*)alloc((size_t)NT * sizeof(float));
    float* x_mid = (float*)alloc((size_t)NT * HH * sizeof(float));

    const int* rp_s = rp2;
    const int* rp_f = rp2 + (NN + 1);
    const int* col_s = col2;
    const int* col_f = col2 + E;

    const int EB = (E + 255) / 256;

    zero_kernel<<<(2 * NN) / 256, 256, 0, stream>>>(cnt2, 2 * NN);
    hist2_kernel<<<2 * EB, 256, 0, stream>>>(ei_s + E, ei_f + E, cnt2, E);
    scanA_kernel<<<128, 256, 0, stream>>>(cnt2, partial);
    scanB_kernel<<<1, 128, 0, stream>>>(partial);
    scanC_kernel<<<128, 256, 0, stream>>>(cnt2, partial, rp2, cur2);
    scatter2_kernel<<<2 * EB, 256, 0, stream>>>(ei_s, ei_f, cur2, col2, E);

    // layer 0
    transform2_kernel<<<NT / 128, 256, 0, stream>>>(
        (const float4*)pred, W0s, a0s, W0f, a0f, h_s, sc_s, h_f, sc_f);
    aggregate_kernel<<<2 * NN, 256, 0, stream>>>(
        (const float4*)pred, (const ushort4*)h_s, sc_s, rp_s, col_s,
        (const ushort4*)h_f, sc_f, rp_f, col_f,
        (const float4*)g0, (const float4*)b0, (float4*)x_mid);

    // layer 1
    transform2_kernel<<<NT / 128, 256, 0, stream>>>(
        (const float4*)x_mid, W1s, a1s, W1f, a1f, h_s, sc_s, h_f, sc_f);
    aggregate_kernel<<<2 * NN, 256, 0, stream>>>(
        (const float4*)x_mid, (const ushort4*)h_s, sc_s, rp_s, col_s,
        (const ushort4*)h_f, sc_f, rp_f, col_f,
        (const float4*)g1, (const float4*)b1, (float4*)d_out);
}

// Round 10
// 272.017 us; speedup vs baseline: 1.3486x; 1.0546x over previous
//
#include <hip/hip_runtime.h>
#include <hip/hip_bf16.h>

#define NN 16384
#define NP1 (NN + 1)
#define TT 4
#define HH 64
#define NT (NN * TT)
#define NEG_SLOPE 0.2f
#define LN_EPS 1e-5f

typedef __attribute__((ext_vector_type(8))) short short8;   // 8 bf16 (4 VGPRs)
typedef __attribute__((ext_vector_type(4))) float f32x4;    // MFMA accumulator

__device__ __forceinline__ float bf2f(unsigned short u) {
    return __uint_as_float((unsigned)u << 16);
}
// f32 -> bf16 RNE
__device__ __forceinline__ unsigned short f2bf(float f) {
    unsigned u = __float_as_uint(f);
    return (unsigned short)((u + 0x7FFF + ((u >> 16) & 1)) >> 16);
}

// ---------------- CSR build (both edge sets fused, PADDED to x16) ----------------

__global__ void zero_kernel(int* __restrict__ a, int n) {
    int i = blockIdx.x * blockDim.x + threadIdx.x;
    if (i < n) a[i] = 0;
}

// pre-fill col with dummy node id NN (pads resolve to exp(-inf)=0 weights)
__global__ void fillcol_kernel(int* __restrict__ a, int n) {
    int i = blockIdx.x * blockDim.x + threadIdx.x;
    if (i < n) a[i] = NN;
}

__global__ void hist2_kernel(const int* __restrict__ dst_s, const int* __restrict__ dst_f,
                             int* __restrict__ cnt2, int E) {
    int e = blockIdx.x * blockDim.x + threadIdx.x;
    if (e < E) {
        atomicAdd(&cnt2[dst_s[e]], 1);
    } else {
        e -= E;
        if (e < E) atomicAdd(&cnt2[NN + dst_f[e]], 1);
    }
}

__device__ __forceinline__ int pad16(int v) { return (v + 15) & ~15; }

// --- fully parallel 3-phase exclusive scan of PADDED cnt2 (2 sets x NN) ---
__global__ __launch_bounds__(256) void scanA_kernel(const int* __restrict__ cnt2,
                                                    int* __restrict__ partial) {
    __shared__ int wsum[4];
    const int lane = threadIdx.x & 63;
    const int wv = threadIdx.x >> 6;
    int v = pad16(cnt2[blockIdx.x * 256 + threadIdx.x]);
#pragma unroll
    for (int off = 32; off > 0; off >>= 1) v += __shfl_xor(v, off, 64);
    if (lane == 0) wsum[wv] = v;
    __syncthreads();
    if (threadIdx.x == 0)
        partial[blockIdx.x] = wsum[0] + wsum[1] + wsum[2] + wsum[3];
}

__global__ __launch_bounds__(128) void scanB_kernel(int* __restrict__ partial) {
    const int lane = threadIdx.x & 63;
    int v = partial[threadIdx.x];
    int inc = v;
#pragma unroll
    for (int off = 1; off < 64; off <<= 1) {
        int t = __shfl_up(inc, off, 64);
        if (lane >= off) inc += t;
    }
    partial[threadIdx.x] = inc - v;
}

__global__ __launch_bounds__(256) void scanC_kernel(const int* __restrict__ cnt2,
                                                    const int* __restrict__ partial,
                                                    int* __restrict__ rp2,
                                                    int* __restrict__ cur2) {
    __shared__ int wsum[4];
    const int lane = threadIdx.x & 63;
    const int wv = threadIdx.x >> 6;
    const int gidx = blockIdx.x * 256 + threadIdx.x;
    const int set = gidx >> 14;
    const int i = gidx & (NN - 1);
    int v = pad16(cnt2[gidx]);
    int inc = v;
#pragma unroll
    for (int off = 1; off < 64; off <<= 1) {
        int t = __shfl_up(inc, off, 64);
        if (lane >= off) inc += t;
    }
    if (lane == 63) wsum[wv] = inc;
    __syncthreads();
    int wbase = 0;
#pragma unroll
    for (int w = 0; w < 4; w++)
        if (w < wv) wbase += wsum[w];
    int excl = (inc - v) + wbase + partial[blockIdx.x];
    int* rp = rp2 + set * (NN + 1);
    rp[i] = excl;
    cur2[gidx] = excl;
    if (i == NN - 1) rp[NN] = excl + v;
}

__global__ void scatter2_kernel(const int* __restrict__ ei_s, const int* __restrict__ ei_f,
                                int* __restrict__ cur2, int* __restrict__ col2,
                                int E, int PCAP) {
    int e = blockIdx.x * blockDim.x + threadIdx.x;
    if (e < E) {
        int d = ei_s[E + e];
        int pos = atomicAdd(&cur2[d], 1);
        col2[pos] = ei_s[e];
    } else {
        e -= E;
        if (e < E) {
            int d = ei_f[E + e];
            int pos = atomicAdd(&cur2[NN + d], 1);
            col2[PCAP + pos] = ei_f[e];
        }
    }
}

// dummy node NN: score -inf (exp->0), h = 0 (finite, no NaN from 0*h)
__global__ void dummy_kernel(unsigned short* __restrict__ h_s, unsigned short* __restrict__ h_f,
                             float* __restrict__ sc_s, float* __restrict__ sc_f) {
    const int t = blockIdx.x;      // 4 blocks
    const int l = threadIdx.x;     // 64 threads
    h_s[((size_t)t * NP1 + NN) * 64 + l] = 0;
    h_f[((size_t)t * NP1 + NN) * 64 + l] = 0;
    if (l == 0) {
        sc_s[t * NP1 + NN] = -INFINITY;
        sc_f[t * NP1 + NN] = -INFINITY;
    }
}

// ------- fused dual transform via MFMA: h_s = x*Ws, h_f = x*Wf + scores ------
// h and sc stored T-MAJOR with NP1 stride: h[t][node][ch], sc[t][node].

__global__ __launch_bounds__(256) void transform2_kernel(
    const float4* __restrict__ x4,
    const float* __restrict__ Ws, const float* __restrict__ as_,
    const float* __restrict__ Wf, const float* __restrict__ af,
    unsigned short* __restrict__ h_s, float* __restrict__ sc_s,
    unsigned short* __restrict__ h_f, float* __restrict__ sc_f) {
    const int lane = threadIdx.x & 63;
    const int wv = threadIdx.x >> 6;
    const int m = lane & 15;
    const int quad = lane >> 4;

    short8 Bs[4][2], Bf[4][2];
#pragma unroll
    for (int c = 0; c < 4; c++) {
#pragma unroll
        for (int ks = 0; ks < 2; ks++) {
#pragma unroll
            for (int j = 0; j < 8; j++) {
                int k = ks * 32 + quad * 8 + j;
                int n = c * 16 + m;
                Bs[c][ks][j] = (short)f2bf(Ws[k * 64 + n]);
                Bf[c][ks][j] = (short)f2bf(Wf[k * 64 + n]);
            }
        }
    }
    float a_s[4], a_f[4];
#pragma unroll
    for (int c = 0; c < 4; c++) { a_s[c] = as_[c * 16 + m]; a_f[c] = af[c * 16 + m]; }

    const int rowbase = blockIdx.x * 128 + wv * 32;
#pragma unroll
    for (int rt = 0; rt < 2; rt++) {
        const int row0 = rowbase + rt * 16;
        const long xbase = (long)(row0 + m) * 16 + quad * 2;
        float4 xa = x4[xbase];
        float4 xb = x4[xbase + 1];
        float4 xc = x4[xbase + 8];
        float4 xd = x4[xbase + 9];
        short8 A0, A1;
        A0[0] = (short)f2bf(xa.x); A0[1] = (short)f2bf(xa.y);
        A0[2] = (short)f2bf(xa.z); A0[3] = (short)f2bf(xa.w);
        A0[4] = (short)f2bf(xb.x); A0[5] = (short)f2bf(xb.y);
        A0[6] = (short)f2bf(xb.z); A0[7] = (short)f2bf(xb.w);
        A1[0] = (short)f2bf(xc.x); A1[1] = (short)f2bf(xc.y);
        A1[2] = (short)f2bf(xc.z); A1[3] = (short)f2bf(xc.w);
        A1[4] = (short)f2bf(xd.x); A1[5] = (short)f2bf(xd.y);
        A1[6] = (short)f2bf(xd.z); A1[7] = (short)f2bf(xd.w);

        f32x4 accs[4], accf[4];
#pragma unroll
        for (int c = 0; c < 4; c++) {
            accs[c] = (f32x4){0.f, 0.f, 0.f, 0.f};
            accf[c] = (f32x4){0.f, 0.f, 0.f, 0.f};
        }
#pragma unroll
        for (int c = 0; c < 4; c++) {
            accs[c] = __builtin_amdgcn_mfma_f32_16x16x32_bf16(A0, Bs[c][0], accs[c], 0, 0, 0);
            accs[c] = __builtin_amdgcn_mfma_f32_16x16x32_bf16(A1, Bs[c][1], accs[c], 0, 0, 0);
            accf[c] = __builtin_amdgcn_mfma_f32_16x16x32_bf16(A0, Bf[c][0], accf[c], 0, 0, 0);
            accf[c] = __builtin_amdgcn_mfma_f32_16x16x32_bf16(A1, Bf[c][1], accf[c], 0, 0, 0);
        }
#pragma unroll
        for (int reg = 0; reg < 4; reg++) {
            const int row = row0 + quad * 4 + reg;
            const int node = row >> 2;
            const int tt = row & 3;
            const long hb = ((long)tt * NP1 + node) * 64;
            float ps = 0.f, pf = 0.f;
#pragma unroll
            for (int c = 0; c < 4; c++) {
                h_s[hb + c * 16 + m] = f2bf(accs[c][reg]);
                h_f[hb + c * 16 + m] = f2bf(accf[c][reg]);
                ps = fmaf(accs[c][reg], a_s[c], ps);
                pf = fmaf(accf[c][reg], a_f[c], pf);
            }
#pragma unroll
            for (int off = 1; off < 16; off <<= 1) {
                ps += __shfl_xor(ps, off, 64);
                pf += __shfl_xor(pf, off, 64);
            }
            if (m == 0) {
                sc_s[tt * NP1 + node] = (ps > 0.f) ? ps : NEG_SLOPE * ps;
                sc_f[tt * NP1 + node] = (pf > 0.f) ? pf : NEG_SLOPE * pf;
            }
        }
    }
}

// ---------------- attention aggregation (per-t sliced, padded, set-merged) ----
// Wave = one (node, t), BOTH edge sets (no LDS, no syncthreads). Block = 4
// waves = 4 nodes at one t. blockIdx%8 -> (t, node-half) for XCD L2 slicing.
// Lane = (u = lane>>4, ci = lane&15): 16 edges/iteration, zero bounds checks
// (CSR padded to x16 with dummy node NN: sc=-inf -> e=0, h=0).

__global__ __launch_bounds__(256) void aggregate_kernel(
    const float4* __restrict__ x4,
    const ushort4* __restrict__ hs4, const float* __restrict__ scs,
    const int* __restrict__ rps, const int* __restrict__ cols,
    const ushort4* __restrict__ hf4, const float* __restrict__ scf,
    const int* __restrict__ rpf, const int* __restrict__ colf,
    const float4* __restrict__ g4, const float4* __restrict__ b4,
    float4* __restrict__ out4) {
    const int wv = threadIdx.x >> 6;
    const int lane = threadIdx.x & 63;
    const int r = blockIdx.x & 7;
    const int t = r >> 1;
    const int half = r & 1;
    const int n = half * (NN / 2) + (blockIdx.x >> 3) * 4 + wv;
    const int u = lane >> 4;
    const int ci = lane & 15;

    const float* sct_s = scs + t * NP1;
    const float* sct_f = scf + t * NP1;
    const ushort4* ht_s = hs4 + (size_t)t * NP1 * 16;
    const ushort4* ht_f = hf4 + (size_t)t * NP1 * 16;

    const int beg_s = rps[n], end_s = rps[n + 1];
    const int beg_f = rpf[n], end_f = rpf[n + 1];

    float den_s = 0.f, den_f = 0.f;
    float4 as = {0.f, 0.f, 0.f, 0.f};
    float4 af = {0.f, 0.f, 0.f, 0.f};

    for (int j = beg_s + u; j < end_s; j += 16) {
        int s0 = cols[j], s1 = cols[j + 4], s2 = cols[j + 8], s3 = cols[j + 12];
        float l0 = sct_s[s0], l1 = sct_s[s1], l2 = sct_s[s2], l3 = sct_s[s3];
        ushort4 h0 = ht_s[s0 * 16 + ci], h1 = ht_s[s1 * 16 + ci],
                h2 = ht_s[s2 * 16 + ci], h3 = ht_s[s3 * 16 + ci];
        float e0 = __expf(l0), e1 = __expf(l1), e2 = __expf(l2), e3 = __expf(l3);
        den_s += (e0 + e1) + (e2 + e3);
        as.x = fmaf(e0, bf2f(h0.x), as.x); as.y = fmaf(e0, bf2f(h0.y), as.y);
        as.z = fmaf(e0, bf2f(h0.z), as.z); as.w = fmaf(e0, bf2f(h0.w), as.w);
        as.x = fmaf(e1, bf2f(h1.x), as.x); as.y = fmaf(e1, bf2f(h1.y), as.y);
        as.z = fmaf(e1, bf2f(h1.z), as.z); as.w = fmaf(e1, bf2f(h1.w), as.w);
        as.x = fmaf(e2, bf2f(h2.x), as.x); as.y = fmaf(e2, bf2f(h2.y), as.y);
        as.z = fmaf(e2, bf2f(h2.z), as.z); as.w = fmaf(e2, bf2f(h2.w), as.w);
        as.x = fmaf(e3, bf2f(h3.x), as.x); as.y = fmaf(e3, bf2f(h3.y), as.y);
        as.z = fmaf(e3, bf2f(h3.z), as.z); as.w = fmaf(e3, bf2f(h3.w), as.w);
    }
    for (int j = beg_f + u; j < end_f; j += 16) {
        int s0 = colf[j], s1 = colf[j + 4], s2 = colf[j + 8], s3 = colf[j + 12];
        float l0 = sct_f[s0], l1 = sct_f[s1], l2 = sct_f[s2], l3 = sct_f[s3];
        ushort4 h0 = ht_f[s0 * 16 + ci], h1 = ht_f[s1 * 16 + ci],
                h2 = ht_f[s2 * 16 + ci], h3 = ht_f[s3 * 16 + ci];
        float e0 = __expf(l0), e1 = __expf(l1), e2 = __expf(l2), e3 = __expf(l3);
        den_f += (e0 + e1) + (e2 + e3);
        af.x = fmaf(e0, bf2f(h0.x), af.x); af.y = fmaf(e0, bf2f(h0.y), af.y);
        af.z = fmaf(e0, bf2f(h0.z), af.z); af.w = fmaf(e0, bf2f(h0.w), af.w);
        af.x = fmaf(e1, bf2f(h1.x), af.x); af.y = fmaf(e1, bf2f(h1.y), af.y);
        af.z = fmaf(e1, bf2f(h1.z), af.z); af.w = fmaf(e1, bf2f(h1.w), af.w);
        af.x = fmaf(e2, bf2f(h2.x), af.x); af.y = fmaf(e2, bf2f(h2.y), af.y);
        af.z = fmaf(e2, bf2f(h2.z), af.z); af.w = fmaf(e2, bf2f(h2.w), af.w);
        af.x = fmaf(e3, bf2f(h3.x), af.x); af.y = fmaf(e3, bf2f(h3.y), af.y);
        af.z = fmaf(e3, bf2f(h3.z), af.z); af.w = fmaf(e3, bf2f(h3.w), af.w);
    }

    // combine the 4 u-groups (xor 16, 32 stay within same ci)
#pragma unroll
    for (int off = 16; off < 64; off <<= 1) {
        den_s += __shfl_xor(den_s, off, 64);
        den_f += __shfl_xor(den_f, off, 64);
        as.x += __shfl_xor(as.x, off, 64);
        as.y += __shfl_xor(as.y, off, 64);
        as.z += __shfl_xor(as.z, off, 64);
        as.w += __shfl_xor(as.w, off, 64);
        af.x += __shfl_xor(af.x, off, 64);
        af.y += __shfl_xor(af.y, off, 64);
        af.z += __shfl_xor(af.z, off, 64);
        af.w += __shfl_xor(af.w, off, 64);
    }
    float4 ms, mf;
    if (end_s > beg_s) {
        float rd = 1.f / den_s;
        ms.x = as.x * rd; ms.y = as.y * rd; ms.z = as.z * rd; ms.w = as.w * rd;
    } else {
        ms.x = ms.y = ms.z = ms.w = 0.f;
    }
    if (end_f > beg_f) {
        float rd = 1.f / den_f;
        mf.x = af.x * rd; mf.y = af.y * rd; mf.z = af.z * rd; mf.w = af.w * rd;
    } else {
        mf.x = mf.y = mf.z = mf.w = 0.f;
    }

    float4 xv = x4[(n * 4 + t) * 16 + ci];   // x[n][t][4*ci..+3]

    float v0 = xv.x + 0.5f * (ms.x + mf.x);
    float v1 = xv.y + 0.5f * (ms.y + mf.y);
    float v2 = xv.z + 0.5f * (ms.z + mf.z);
    float v3 = xv.w + 0.5f * (ms.w + mf.w);

    // LayerNorm over H=64 within the 16-lane ci group (all u groups identical)
    float sum = (v0 + v1) + (v2 + v3);
#pragma unroll
    for (int off = 1; off < 16; off <<= 1) sum += __shfl_xor(sum, off, 64);
    float mu = sum * (1.f / 64.f);
    float d0 = v0 - mu, d1 = v1 - mu, d2 = v2 - mu, d3 = v3 - mu;
    float var = (d0 * d0 + d1 * d1) + (d2 * d2 + d3 * d3);
#pragma unroll
    for (int off = 1; off < 16; off <<= 1) var += __shfl_xor(var, off, 64);
    var *= (1.f / 64.f);
    float inv = rsqrtf(var + LN_EPS);
    float4 gv = g4[ci], bv = b4[ci];
    float4 o;
    o.x = d0 * inv * gv.x + bv.x;
    o.y = d1 * inv * gv.y + bv.y;
    o.z = d2 * inv * gv.z + bv.z;
    o.w = d3 * inv * gv.w + bv.w;
    if (u == 0) out4[(n * 4 + t) * 16 + ci] = o;
}

// ---------------- launch ----------------

extern "C" void kernel_launch(void* const* d_in, const int* in_sizes, int n_in,
                              void* d_out, int out_size, void* d_ws, size_t ws_size,
                              hipStream_t stream) {
    const float* pred = (const float*)d_in[0];
    const int* ei_s = (const int*)d_in[1];
    const int* ei_f = (const int*)d_in[2];
    const float* W0s = (const float*)d_in[3];
    const float* a0s = (const float*)d_in[4];
    const float* W0f = (const float*)d_in[5];
    const float* a0f = (const float*)d_in[6];
    const float* g0  = (const float*)d_in[7];
    const float* b0  = (const float*)d_in[8];
    const float* W1s = (const float*)d_in[9];
    const float* a1s = (const float*)d_in[10];
    const float* W1f = (const float*)d_in[11];
    const float* a1f = (const float*)d_in[12];
    const float* g1  = (const float*)d_in[13];
    const float* b1  = (const float*)d_in[14];
    const int E = in_sizes[1] / 2;             // 262144
    const int PCAP = E + 15 * NN;              // padded CSR capacity per set

    char* ws = (char*)d_ws;
    auto alloc = [&](size_t bytes) {
        char* p = ws;
        ws += (bytes + 255) & ~(size_t)255;
        return p;
    };
    int* cnt2 = (int*)alloc((size_t)2 * NN * sizeof(int));
    int* rp2  = (int*)alloc((size_t)2 * (NN + 1) * sizeof(int));
    int* cur2 = (int*)alloc((size_t)2 * NN * sizeof(int));
    int* col2 = (int*)alloc((size_t)2 * PCAP * sizeof(int));
    int* partial = (int*)alloc(128 * sizeof(int));
    unsigned short* h_s = (unsigned short*)alloc((size_t)TT * NP1 * HH * sizeof(unsigned short));
    unsigned short* h_f = (unsigned short*)alloc((size_t)TT * NP1 * HH * sizeof(unsigned short));
    float* sc_s = (float*)alloc((size_t)TT * NP1 * sizeof(float));
    float* sc_f = (float*)alloc((size_t)TT * NP1 * sizeof(float));
    float* x_mid = (float*)alloc((size_t)NT * HH * sizeof(float));

    const int* rp_s = rp2;
    const int* rp_f = rp2 + (NN + 1);
    const int* col_s = col2;
    const int* col_f = col2 + PCAP;

    const int EB = (E + 255) / 256;

    zero_kernel<<<(2 * NN) / 256, 256, 0, stream>>>(cnt2, 2 * NN);
    fillcol_kernel<<<(2 * PCAP + 255) / 256, 256, 0, stream>>>(col2, 2 * PCAP);
    hist2_kernel<<<2 * EB, 256, 0, stream>>>(ei_s + E, ei_f + E, cnt2, E);
    scanA_kernel<<<128, 256, 0, stream>>>(cnt2, partial);
    scanB_kernel<<<1, 128, 0, stream>>>(partial);
    scanC_kernel<<<128, 256, 0, stream>>>(cnt2, partial, rp2, cur2);
    scatter2_kernel<<<2 * EB, 256, 0, stream>>>(ei_s, ei_f, cur2, col2, E, PCAP);
    dummy_kernel<<<TT, 64, 0, stream>>>(h_s, h_f, sc_s, sc_f);

    // layer 0
    transform2_kernel<<<NT / 128, 256, 0, stream>>>(
        (const float4*)pred, W0s, a0s, W0f, a0f, h_s, sc_s, h_f, sc_f);
    aggregate_kernel<<<NN, 256, 0, stream>>>(
        (const float4*)pred, (const ushort4*)h_s, sc_s, rp_s, col_s,
        (const ushort4*)h_f, sc_f, rp_f, col_f,
        (const float4*)g0, (const float4*)b0, (float4*)x_mid);

    // layer 1
    transform2_kernel<<<NT / 128, 256, 0, stream>>>(
        (const float4*)x_mid, W1s, a1s, W1f, a1f, h_s, sc_s, h_f, sc_f);
    aggregate_kernel<<<NN, 256, 0, stream>>>(
        (const float4*)x_mid, (const ushort4*)h_s, sc_s, rp_s, col_s,
        (const ushort4*)h_f, sc_f, rp_f, col_f,
        (const float4*)g1, (const float4*)b1, (float4*)d_out);
}

// Round 11
// 260.425 us; speedup vs baseline: 1.4087x; 1.0445x over previous
//
#include <hip/hip_runtime.h>
#include <hip/hip_bf16.h>

#define NN 16384
#define TT 4
#define HH 64
#define NT (NN * TT)
#define NROWS (NT + TT)          // +4 dummy rows for pad node NN
#define NEG_SLOPE 0.2f
#define LN_EPS 1e-5f

typedef __attribute__((ext_vector_type(8))) short short8;   // 8 bf16 (4 VGPRs)
typedef __attribute__((ext_vector_type(4))) float f32x4;    // MFMA accumulator

__device__ __forceinline__ float bf2f(unsigned short u) {
    return __uint_as_float((unsigned)u << 16);
}
// f32 -> bf16 RNE
__device__ __forceinline__ unsigned short f2bf(float f) {
    unsigned u = __float_as_uint(f);
    return (unsigned short)((u + 0x7FFF + ((u >> 16) & 1)) >> 16);
}

// ---------------- CSR build (both edge sets fused, PADDED to x8) ----------------

__global__ void zero_kernel(int* __restrict__ a, int n) {
    int i = blockIdx.x * blockDim.x + threadIdx.x;
    if (i < n) a[i] = 0;
}

// pre-fill col with dummy node id NN (pads resolve to ex=0, hp=0)
__global__ void fillcol_kernel(int* __restrict__ a, int n) {
    int i = blockIdx.x * blockDim.x + threadIdx.x;
    if (i < n) a[i] = NN;
}

__global__ void hist2_kernel(const int* __restrict__ dst_s, const int* __restrict__ dst_f,
                             int* __restrict__ cnt2, int E) {
    int e = blockIdx.x * blockDim.x + threadIdx.x;
    if (e < E) {
        atomicAdd(&cnt2[dst_s[e]], 1);
    } else {
        e -= E;
        if (e < E) atomicAdd(&cnt2[NN + dst_f[e]], 1);
    }
}

__device__ __forceinline__ int pad8(int v) { return (v + 7) & ~7; }

// --- fully parallel 3-phase exclusive scan of PADDED cnt2 (2 sets x NN) ---
__global__ __launch_bounds__(256) void scanA_kernel(const int* __restrict__ cnt2,
                                                    int* __restrict__ partial) {
    __shared__ int wsum[4];
    const int lane = threadIdx.x & 63;
    const int wv = threadIdx.x >> 6;
    int v = pad8(cnt2[blockIdx.x * 256 + threadIdx.x]);
#pragma unroll
    for (int off = 32; off > 0; off >>= 1) v += __shfl_xor(v, off, 64);
    if (lane == 0) wsum[wv] = v;
    __syncthreads();
    if (threadIdx.x == 0)
        partial[blockIdx.x] = wsum[0] + wsum[1] + wsum[2] + wsum[3];
}

__global__ __launch_bounds__(128) void scanB_kernel(int* __restrict__ partial) {
    const int lane = threadIdx.x & 63;
    int v = partial[threadIdx.x];
    int inc = v;
#pragma unroll
    for (int off = 1; off < 64; off <<= 1) {
        int t = __shfl_up(inc, off, 64);
        if (lane >= off) inc += t;
    }
    partial[threadIdx.x] = inc - v;
}

__global__ __launch_bounds__(256) void scanC_kernel(const int* __restrict__ cnt2,
                                                    const int* __restrict__ partial,
                                                    int* __restrict__ rp2,
                                                    int* __restrict__ cur2) {
    __shared__ int wsum[4];
    const int lane = threadIdx.x & 63;
    const int wv = threadIdx.x >> 6;
    const int gidx = blockIdx.x * 256 + threadIdx.x;
    const int set = gidx >> 14;
    const int i = gidx & (NN - 1);
    int v = pad8(cnt2[gidx]);
    int inc = v;
#pragma unroll
    for (int off = 1; off < 64; off <<= 1) {
        int t = __shfl_up(inc, off, 64);
        if (lane >= off) inc += t;
    }
    if (lane == 63) wsum[wv] = inc;
    __syncthreads();
    int wbase = 0;
#pragma unroll
    for (int w = 0; w < 4; w++)
        if (w < wv) wbase += wsum[w];
    int excl = (inc - v) + wbase + partial[blockIdx.x];
    int* rp = rp2 + set * (NN + 1);
    rp[i] = excl;
    cur2[gidx] = excl;
    if (i == NN - 1) rp[NN] = excl + v;
}

__global__ void scatter2_kernel(const int* __restrict__ ei_s, const int* __restrict__ ei_f,
                                int* __restrict__ cur2, int* __restrict__ col2,
                                int E, int PCAP) {
    int e = blockIdx.x * blockDim.x + threadIdx.x;
    if (e < E) {
        int d = ei_s[E + e];
        int pos = atomicAdd(&cur2[d], 1);
        col2[pos] = ei_s[e];
    } else {
        e -= E;
        if (e < E) {
            int d = ei_f[E + e];
            int pos = atomicAdd(&cur2[NN + d], 1);
            col2[PCAP + pos] = ei_f[e];
        }
    }
}

// dummy node NN (rows NT..NT+3): ex = 0 (zero weight), hp = 0
__global__ void dummy_kernel(unsigned short* __restrict__ hp_s, unsigned short* __restrict__ hp_f,
                             float* __restrict__ ex_s, float* __restrict__ ex_f) {
    const int t = blockIdx.x;      // 4 blocks
    const int l = threadIdx.x;     // 64 threads
    hp_s[(size_t)(NT + t) * 64 + l] = 0;
    hp_f[(size_t)(NT + t) * 64 + l] = 0;
    if (l == 0) {
        ex_s[NT + t] = 0.f;
        ex_f[NT + t] = 0.f;
    }
}

// ------- fused dual transform via MFMA + premultiplied-exp outputs ----------
// hp = bf16(e * h), ex = e = exp(lrelu(h . a)) per row (row = node*4 + t).
// v_mfma_f32_16x16x32_bf16; A[m=lane&15][k=quad*8+j]; B[k][n=lane&15];
// C/D col=lane&15, row=quad*4+reg. Wave = 32 rows; block = 128 rows.

__global__ __launch_bounds__(256) void transform2_kernel(
    const float4* __restrict__ x4,
    const float* __restrict__ Ws, const float* __restrict__ as_,
    const float* __restrict__ Wf, const float* __restrict__ af,
    unsigned short* __restrict__ hp_s, float* __restrict__ ex_s,
    unsigned short* __restrict__ hp_f, float* __restrict__ ex_f) {
    const int lane = threadIdx.x & 63;
    const int wv = threadIdx.x >> 6;
    const int m = lane & 15;
    const int quad = lane >> 4;

    short8 Bs[4][2], Bf[4][2];
#pragma unroll
    for (int c = 0; c < 4; c++) {
#pragma unroll
        for (int ks = 0; ks < 2; ks++) {
#pragma unroll
            for (int j = 0; j < 8; j++) {
                int k = ks * 32 + quad * 8 + j;
                int n = c * 16 + m;
                Bs[c][ks][j] = (short)f2bf(Ws[k * 64 + n]);
                Bf[c][ks][j] = (short)f2bf(Wf[k * 64 + n]);
            }
        }
    }
    float a_s[4], a_f[4];
#pragma unroll
    for (int c = 0; c < 4; c++) { a_s[c] = as_[c * 16 + m]; a_f[c] = af[c * 16 + m]; }

    const int rowbase = blockIdx.x * 128 + wv * 32;
#pragma unroll
    for (int rt = 0; rt < 2; rt++) {
        const int row0 = rowbase + rt * 16;
        const long xbase = (long)(row0 + m) * 16 + quad * 2;
        float4 xa = x4[xbase];
        float4 xb = x4[xbase + 1];
        float4 xc = x4[xbase + 8];
        float4 xd = x4[xbase + 9];
        short8 A0, A1;
        A0[0] = (short)f2bf(xa.x); A0[1] = (short)f2bf(xa.y);
        A0[2] = (short)f2bf(xa.z); A0[3] = (short)f2bf(xa.w);
        A0[4] = (short)f2bf(xb.x); A0[5] = (short)f2bf(xb.y);
        A0[6] = (short)f2bf(xb.z); A0[7] = (short)f2bf(xb.w);
        A1[0] = (short)f2bf(xc.x); A1[1] = (short)f2bf(xc.y);
        A1[2] = (short)f2bf(xc.z); A1[3] = (short)f2bf(xc.w);
        A1[4] = (short)f2bf(xd.x); A1[5] = (short)f2bf(xd.y);
        A1[6] = (short)f2bf(xd.z); A1[7] = (short)f2bf(xd.w);

        f32x4 accs[4], accf[4];
#pragma unroll
        for (int c = 0; c < 4; c++) {
            accs[c] = (f32x4){0.f, 0.f, 0.f, 0.f};
            accf[c] = (f32x4){0.f, 0.f, 0.f, 0.f};
        }
#pragma unroll
        for (int c = 0; c < 4; c++) {
            accs[c] = __builtin_amdgcn_mfma_f32_16x16x32_bf16(A0, Bs[c][0], accs[c], 0, 0, 0);
            accs[c] = __builtin_amdgcn_mfma_f32_16x16x32_bf16(A1, Bs[c][1], accs[c], 0, 0, 0);
            accf[c] = __builtin_amdgcn_mfma_f32_16x16x32_bf16(A0, Bf[c][0], accf[c], 0, 0, 0);
            accf[c] = __builtin_amdgcn_mfma_f32_16x16x32_bf16(A1, Bf[c][1], accf[c], 0, 0, 0);
        }
#pragma unroll
        for (int reg = 0; reg < 4; reg++) {
            const int row = row0 + quad * 4 + reg;
            float ps = 0.f, pf = 0.f;
#pragma unroll
            for (int c = 0; c < 4; c++) {
                ps = fmaf(accs[c][reg], a_s[c], ps);
                pf = fmaf(accf[c][reg], a_f[c], pf);
            }
            // butterfly: ALL 16 lanes of the quad-group get the full sum
#pragma unroll
            for (int off = 1; off < 16; off <<= 1) {
                ps += __shfl_xor(ps, off, 64);
                pf += __shfl_xor(pf, off, 64);
            }
            ps = (ps > 0.f) ? ps : NEG_SLOPE * ps;   // LeakyReLU
            pf = (pf > 0.f) ? pf : NEG_SLOPE * pf;
            float es = __expf(ps);
            float ef = __expf(pf);
#pragma unroll
            for (int c = 0; c < 4; c++) {
                hp_s[(long)row * 64 + c * 16 + m] = f2bf(es * accs[c][reg]);
                hp_f[(long)row * 64 + c * 16 + m] = f2bf(ef * accf[c][reg]);
            }
            if (m == 0) {
                ex_s[row] = es;
                ex_f[row] = ef;
            }
        }
    }
}

// ---------------- attention aggregation (all-t wave, premultiplied) ----------
// Wave = one (node, edge-set), lane = (t = lane>>4, ci = lane&15): each edge
// visited ONCE, 512 B/edge (ushort4/lane). Premultiplied hp => inner loop is
// den += ex  and  acc += bf16->f32 (no exp, no mul). Padded-8 CSR: no bounds
// checks (dummy node ex=0, hp=0). No cross-lane message reduce (each lane
// walks all edges for its channels). Block = 2 nodes x 2 sets; set-f wave
// hands its message to set-s via LDS.

__global__ __launch_bounds__(256) void aggregate_kernel(
    const float4* __restrict__ x4,
    const ushort4* __restrict__ hps4, const float* __restrict__ exs,
    const int* __restrict__ rps, const int* __restrict__ cols,
    const ushort4* __restrict__ hpf4, const float* __restrict__ exf,
    const int* __restrict__ rpf, const int* __restrict__ colf,
    const float4* __restrict__ g4, const float4* __restrict__ b4,
    float4* __restrict__ out4) {
    __shared__ float4 msgF[2][64];
    const int wv = threadIdx.x >> 6;
    const int lane = threadIdx.x & 63;
    const int slot = wv >> 1;              // node slot in block (0/1)
    const int set = wv & 1;                // 0 = structural, 1 = functional
    const int n = blockIdx.x * 2 + slot;
    const int t = lane >> 4;
    const int ci = lane & 15;

    const ushort4* hp = set ? hpf4 : hps4;
    const float* ex = set ? exf : exs;
    const int* rp = set ? rpf : rps;
    const int* col = set ? colf : cols;

    const int beg = rp[n], end = rp[n + 1];
    float den = 0.f;
    float4 acc = {0.f, 0.f, 0.f, 0.f};

    for (int j = beg; j < end; j += 8) {
        int s[8];
#pragma unroll
        for (int k = 0; k < 8; k++) s[k] = col[j + k];
        int r[8];
#pragma unroll
        for (int k = 0; k < 8; k++) r[k] = s[k] * 4 + t;
        float e[8];
#pragma unroll
        for (int k = 0; k < 8; k++) e[k] = ex[r[k]];
        ushort4 hh[8];
#pragma unroll
        for (int k = 0; k < 8; k++) hh[k] = hp[r[k] * 16 + ci];
#pragma unroll
        for (int k = 0; k < 8; k++) {
            den += e[k];
            acc.x += bf2f(hh[k].x);
            acc.y += bf2f(hh[k].y);
            acc.z += bf2f(hh[k].z);
            acc.w += bf2f(hh[k].w);
        }
    }

    float4 msg;
    if (end > beg) {
        float rd = 1.f / den;
        msg.x = acc.x * rd; msg.y = acc.y * rd; msg.z = acc.z * rd; msg.w = acc.w * rd;
    } else {
        msg.x = msg.y = msg.z = msg.w = 0.f;
    }

    if (set == 1) msgF[slot][lane] = msg;
    __syncthreads();
    if (set == 1) return;

    float4 mf = msgF[slot][lane];
    float4 xv = x4[(n * 4 + t) * 16 + ci];   // x[n][t][4*ci..+3]

    float v0 = xv.x + 0.5f * (msg.x + mf.x);
    float v1 = xv.y + 0.5f * (msg.y + mf.y);
    float v2 = xv.z + 0.5f * (msg.z + mf.z);
    float v3 = xv.w + 0.5f * (msg.w + mf.w);

    // LayerNorm over H=64 within the 16-lane ci group (t constant per group)
    float sum = (v0 + v1) + (v2 + v3);
#pragma unroll
    for (int off = 1; off < 16; off <<= 1) sum += __shfl_xor(sum, off, 64);
    float mu = sum * (1.f / 64.f);
    float d0 = v0 - mu, d1 = v1 - mu, d2 = v2 - mu, d3 = v3 - mu;
    float var = (d0 * d0 + d1 * d1) + (d2 * d2 + d3 * d3);
#pragma unroll
    for (int off = 1; off < 16; off <<= 1) var += __shfl_xor(var, off, 64);
    var *= (1.f / 64.f);
    float inv = rsqrtf(var + LN_EPS);
    float4 gv = g4[ci], bv = b4[ci];
    float4 o;
    o.x = d0 * inv * gv.x + bv.x;
    o.y = d1 * inv * gv.y + bv.y;
    o.z = d2 * inv * gv.z + bv.z;
    o.w = d3 * inv * gv.w + bv.w;
    out4[(n * 4 + t) * 16 + ci] = o;
}

// ---------------- launch ----------------

extern "C" void kernel_launch(void* const* d_in, const int* in_sizes, int n_in,
                              void* d_out, int out_size, void* d_ws, size_t ws_size,
                              hipStream_t stream) {
    const float* pred = (const float*)d_in[0];
    const int* ei_s = (const int*)d_in[1];
    const int* ei_f = (const int*)d_in[2];
    const float* W0s = (const float*)d_in[3];
    const float* a0s = (const float*)d_in[4];
    const float* W0f = (const float*)d_in[5];
    const float* a0f = (const float*)d_in[6];
    const float* g0  = (const float*)d_in[7];
    const float* b0  = (const float*)d_in[8];
    const float* W1s = (const float*)d_in[9];
    const float* a1s = (const float*)d_in[10];
    const float* W1f = (const float*)d_in[11];
    const float* a1f = (const float*)d_in[12];
    const float* g1  = (const float*)d_in[13];
    const float* b1  = (const float*)d_in[14];
    const int E = in_sizes[1] / 2;             // 262144
    const int PCAP = E + 7 * NN;               // padded-8 CSR capacity per set

    char* ws = (char*)d_ws;
    auto alloc = [&](size_t bytes) {
        char* p = ws;
        ws += (bytes + 255) & ~(size_t)255;
        return p;
    };
    int* cnt2 = (int*)alloc((size_t)2 * NN * sizeof(int));
    int* rp2  = (int*)alloc((size_t)2 * (NN + 1) * sizeof(int));
    int* cur2 = (int*)alloc((size_t)2 * NN * sizeof(int));
    int* col2 = (int*)alloc((size_t)2 * PCAP * sizeof(int));
    int* partial = (int*)alloc(128 * sizeof(int));
    unsigned short* hp_s = (unsigned short*)alloc((size_t)NROWS * HH * sizeof(unsigned short));
    unsigned short* hp_f = (unsigned short*)alloc((size_t)NROWS * HH * sizeof(unsigned short));
    float* ex_s = (float*)alloc((size_t)NROWS * sizeof(float));
    float* ex_f = (float*)alloc((size_t)NROWS * sizeof(float));
    float* x_mid = (float*)alloc((size_t)NT * HH * sizeof(float));

    const int* rp_s = rp2;
    const int* rp_f = rp2 + (NN + 1);
    const int* col_s = col2;
    const int* col_f = col2 + PCAP;

    const int EB = (E + 255) / 256;

    zero_kernel<<<(2 * NN) / 256, 256, 0, stream>>>(cnt2, 2 * NN);
    fillcol_kernel<<<(2 * PCAP + 255) / 256, 256, 0, stream>>>(col2, 2 * PCAP);
    hist2_kernel<<<2 * EB, 256, 0, stream>>>(ei_s + E, ei_f + E, cnt2, E);
    scanA_kernel<<<128, 256, 0, stream>>>(cnt2, partial);
    scanB_kernel<<<1, 128, 0, stream>>>(partial);
    scanC_kernel<<<128, 256, 0, stream>>>(cnt2, partial, rp2, cur2);
    scatter2_kernel<<<2 * EB, 256, 0, stream>>>(ei_s, ei_f, cur2, col2, E, PCAP);
    dummy_kernel<<<TT, 64, 0, stream>>>(hp_s, hp_f, ex_s, ex_f);

    // layer 0
    transform2_kernel<<<NT / 128, 256, 0, stream>>>(
        (const float4*)pred, W0s, a0s, W0f, a0f, hp_s, ex_s, hp_f, ex_f);
    aggregate_kernel<<<NN / 2, 256, 0, stream>>>(
        (const float4*)pred, (const ushort4*)hp_s, ex_s, rp_s, col_s,
        (const ushort4*)hp_f, ex_f, rp_f, col_f,
        (const float4*)g0, (const float4*)b0, (float4*)x_mid);

    // layer 1
    transform2_kernel<<<NT / 128, 256, 0, stream>>>(
        (const float4*)x_mid, W1s, a1s, W1f, a1f, hp_s, ex_s, hp_f, ex_f);
    aggregate_kernel<<<NN / 2, 256, 0, stream>>>(
        (const float4*)x_mid, (const ushort4*)hp_s, ex_s, rp_s, col_s,
        (const ushort4*)hp_f, ex_f, rp_f, col_f,
        (const float4*)g1, (const float4*)b1, (float4*)d_out);
}